// Round 4
// baseline (842.234 us; speedup 1.0000x reference)
//
#include <hip/hip_runtime.h>

// ---------------------------------------------------------------------------
// Atten2Map on MI355X (gfx950)
// shapes: nb=4 nloc=256 nnei=128 ni=128, ND=32 NH=8, NCH=512, NBL=1024
//
// Kd: detect nlist_mask dtype (int32 vs byte-packed bool) -> flag in ws
// K0: Wt[c][t] = W[t][c] * 32^-0.25, pre-split bf16 hi/lo   (ws, 256 KB)
// K1: per-(b,l): QK[c][j] = (g2 @ W)^T via split-bf16 MFMA  (ws, 256 KB/bl)
// K2: per-(b,l): 8 waves = 8 heads; QK^T (one K=32 MFMA/tile, x3 split),
//     masked softmax over k, *sw[q]*sw[k], stage all heads in LDS, epilogue
//     multiplies h2h2t[q][k] and writes h-contiguous 32B to out[b,l,q,k,h].
//
// R1 fix: read nlist_mask as int32 (harness: "integer -> const int*").
// R3: rounds 2-3 lost to GPU acquisition timeouts; added runtime mask-dtype
//     detection so correctness is settled regardless of bool staging.
// ---------------------------------------------------------------------------

typedef __attribute__((ext_vector_type(8))) short bf16x8;
typedef __attribute__((ext_vector_type(4))) float f32x4;

#define NNEI 128
#define NI   128
#define NCH  512
#define NBL  1024
#define QK_SLAB_FLOATS (NNEI * NCH)          // 65536 floats = 256 KB
#define QK_SLAB_BYTES  (QK_SLAB_FLOATS * 4)
#define WT_BYTES       (NCH * NI * 2 * 2)    // hi+lo bf16 = 262144 B
#define FLAG_BYTES     256

__device__ __forceinline__ unsigned short f2bf(float x) {
    unsigned u = __builtin_bit_cast(unsigned, x);
    u += 0x7FFFu + ((u >> 16) & 1u);              // RNE
    return (unsigned short)(u >> 16);
}
__device__ __forceinline__ float bf2f(unsigned short b) {
    unsigned u = ((unsigned)b) << 16;
    return __builtin_bit_cast(float, u);
}

// ------------------------------- Kd ----------------------------------------
// If mask is int32, every word is 0 or 1. If byte-packed bool, words with
// high bytes set appear w.p. ~1. flag=1 -> byte-packed.
__global__ void k_detect_mask(const unsigned int* __restrict__ m, int nwords,
                              int* __restrict__ flag) {
    __shared__ int f;
    if (threadIdx.x == 0) f = 0;
    __syncthreads();
    int acc = 0;
    for (int i = threadIdx.x; i < nwords; i += blockDim.x)
        acc |= (m[i] & ~1u) ? 1 : 0;
    if (acc) atomicOr(&f, 1);
    __syncthreads();
    if (threadIdx.x == 0) *flag = f;
}

// ------------------------------- K0 ----------------------------------------
__global__ void k0_prep_w(const float* __restrict__ W,
                          unsigned short* __restrict__ wt_hi,
                          unsigned short* __restrict__ wt_lo) {
    int g = blockIdx.x * 256 + threadIdx.x;        // 65536 elements
    int c = g >> 7, t = g & 127;
    float w = W[t * NCH + c] * 0.42044820762685725f;   // 32^-0.25
    unsigned short hb = f2bf(w);
    float hf = bf2f(hb);
    wt_hi[g] = hb;
    wt_lo[g] = f2bf(w - hf);
}

// ------------------------------- K1 ----------------------------------------
// grid = cnt (one WG per (b,l)); 512 threads = 8 waves (2 M x 4 N).
// LDS: A(g2) 128x128 bf16 hi/lo + B(Wt rows) 128x128 hi/lo = 128 KiB.
__device__ __forceinline__ bf16x8 ldsfrag(const unsigned short* base, int row, int t0) {
    int byte = row * 256 + ((2 * t0) ^ ((row & 7) << 4));   // XOR swizzle (T2)
    return *(const bf16x8*)((const char*)base + byte);
}

__launch_bounds__(512, 2)
__global__ void k1_gemm_qk(const float* __restrict__ g2,
                           const unsigned short* __restrict__ wt_hi,
                           const unsigned short* __restrict__ wt_lo,
                           float* __restrict__ qk, int bl0) {
    __shared__ unsigned short Ahi[128 * 128], Alo[128 * 128];
    __shared__ unsigned short Bhi[128 * 128], Blo[128 * 128];

    const int tid  = threadIdx.x;
    const int lane = tid & 63;
    const int w    = tid >> 6;
    const int wm   = w >> 2;        // 0..1 -> 64 rows of j
    const int wn   = w & 3;         // 0..3 -> 32 cols of c
    const int bl   = bl0 + blockIdx.x;

    const float* A = g2 + (size_t)bl * NNEI * NI;
    float* outp    = qk + (size_t)blockIdx.x * QK_SLAB_FLOATS;

    // stage A = g2 tile (f32 -> bf16 hi/lo, swizzled)
#pragma unroll
    for (int it = 0; it < 8; ++it) {
        int j  = it * 16 + (tid >> 5);
        int t4 = (tid & 31) * 4;
        float4 v = *(const float4*)(A + j * 128 + t4);
        unsigned short h0 = f2bf(v.x), h1 = f2bf(v.y), h2_ = f2bf(v.z), h3 = f2bf(v.w);
        ushort4 hv = {h0, h1, h2_, h3};
        ushort4 lv = {f2bf(v.x - bf2f(h0)), f2bf(v.y - bf2f(h1)),
                      f2bf(v.z - bf2f(h2_)), f2bf(v.w - bf2f(h3))};
        int byte = j * 256 + ((2 * t4) ^ ((j & 7) << 4));
        *(ushort4*)((char*)Ahi + byte) = hv;
        *(ushort4*)((char*)Alo + byte) = lv;
    }

    for (int nb = 0; nb < 4; ++nb) {
        __syncthreads();
        // stage B = Wt rows [nb*128, nb*128+128), already bf16 hi/lo in ws
#pragma unroll
        for (int u = 0; u < 4; ++u) {
            int flat = u * 512 + tid;            // 16-byte units (2048 total)
            int c = flat >> 4, blk = flat & 15;
            int src  = (nb * 128 + c) * 128 + blk * 8;   // shorts
            int byte = c * 256 + ((blk * 16) ^ ((c & 7) << 4));
            *(uint4*)((char*)Bhi + byte) = *(const uint4*)(wt_hi + src);
            *(uint4*)((char*)Blo + byte) = *(const uint4*)(wt_lo + src);
        }
        __syncthreads();

        f32x4 acc[4][2];
#pragma unroll
        for (int m = 0; m < 4; ++m)
#pragma unroll
            for (int n = 0; n < 2; ++n) acc[m][n] = (f32x4)0.0f;

#pragma unroll
        for (int kk = 0; kk < 4; ++kk) {
            int t0 = kk * 32 + (lane >> 4) * 8;
            bf16x8 ah[4], al[4], bh[2], blo[2];
#pragma unroll
            for (int m = 0; m < 4; ++m) {
                int row = wm * 64 + m * 16 + (lane & 15);
                ah[m] = ldsfrag(Ahi, row, t0);
                al[m] = ldsfrag(Alo, row, t0);
            }
#pragma unroll
            for (int n = 0; n < 2; ++n) {
                int row = wn * 32 + n * 16 + (lane & 15);
                bh[n]  = ldsfrag(Bhi, row, t0);
                blo[n] = ldsfrag(Blo, row, t0);
            }
#pragma unroll
            for (int m = 0; m < 4; ++m)
#pragma unroll
                for (int n = 0; n < 2; ++n) {
                    acc[m][n] = __builtin_amdgcn_mfma_f32_16x16x32_bf16(ah[m], bh[n],  acc[m][n], 0, 0, 0);
                    acc[m][n] = __builtin_amdgcn_mfma_f32_16x16x32_bf16(ah[m], blo[n], acc[m][n], 0, 0, 0);
                    acc[m][n] = __builtin_amdgcn_mfma_f32_16x16x32_bf16(al[m], bh[n],  acc[m][n], 0, 0, 0);
                }
        }
        // write QK^T slab: qk[c][j], C-frag reg r = row j0+r -> contiguous j
#pragma unroll
        for (int m = 0; m < 4; ++m)
#pragma unroll
            for (int n = 0; n < 2; ++n) {
                int c  = nb * 128 + wn * 32 + n * 16 + (lane & 15);
                int j0 = wm * 64 + m * 16 + (lane >> 4) * 4;
                *(f32x4*)(outp + c * 128 + j0) = acc[m][n];
            }
    }
}

// ------------------------------- K2 ----------------------------------------
// grid = cnt; 512 threads = 8 waves; wave w handles head h = w.
// LDS: S8[32][128*9] f32 (pad-9: odd stride -> conflict-light) + small tables.
__launch_bounds__(512, 2)
__global__ void k2_attn_out(const float* __restrict__ qk,
                            const float* __restrict__ h2,
                            const int* __restrict__ msk,
                            const float* __restrict__ sw,
                            const int* __restrict__ mask_is_bytes,
                            float* __restrict__ outp, int bl0) {
    __shared__ float S8[32][1152];        // [q_local][k*9 + h]
    __shared__ float h2t[3][128];
    __shared__ float rowsw[128], colbias[128], colsw[128];

    const int tid  = threadIdx.x;
    const int lane = tid & 63;
    const int h    = tid >> 6;            // wave id == head
    const int bl   = bl0 + blockIdx.x;
    const float* slab = qk + (size_t)blockIdx.x * QK_SLAB_FLOATS;

    if (tid < 128) {
        int  idx = bl * 128 + tid;
        bool mk  = (*mask_is_bytes)
                     ? (((const unsigned char*)msk)[idx] != 0)
                     : (msk[idx] != 0);
        float s  = sw[idx];
        rowsw[tid]   = mk ? s : 0.0f;     // sw[q] * mask_c
        colbias[tid] = mk ? 0.0f : -1e30f;
        colsw[tid]   = s;                 // sw[k] (masked k are 0 anyway)
    }
    if (tid < 384) {
        int c = tid >> 7, j = tid & 127;
        h2t[c][j] = h2[(size_t)bl * 384 + j * 3 + c];
    }
    __syncthreads();

    const int colk = lane & 15;
    const int dgrp = lane >> 4;
    const int d0   = dgrp * 8;

    float cbias[8], cswr[8];
#pragma unroll
    for (int n = 0; n < 8; ++n) {
        int k = n * 16 + colk;
        cbias[n] = colbias[k];
        cswr[n]  = colsw[k];
    }

    // K fragments for this head, register-resident (hi/lo split)
    bf16x8 kh[8], kl[8];
#pragma unroll
    for (int n = 0; n < 8; ++n) {
#pragma unroll
        for (int i = 0; i < 8; ++i) {
            float v = slab[((d0 + i) * 16 + 8 + h) * 128 + n * 16 + colk];
            unsigned short hb = f2bf(v);
            kh[n][i] = (short)hb;
            kl[n][i] = (short)f2bf(v - bf2f(hb));
        }
    }

    for (int qt = 0; qt < 4; ++qt) {
        // Q fragments for this q-tile
        bf16x8 qh[2], ql[2];
#pragma unroll
        for (int m = 0; m < 2; ++m) {
#pragma unroll
            for (int i = 0; i < 8; ++i) {
                float v = slab[((d0 + i) * 16 + h) * 128 + qt * 32 + m * 16 + colk];
                unsigned short hb = f2bf(v);
                qh[m][i] = (short)hb;
                ql[m][i] = (short)f2bf(v - bf2f(hb));
            }
        }

        f32x4 acc[2][8];
#pragma unroll
        for (int m = 0; m < 2; ++m)
#pragma unroll
            for (int n = 0; n < 8; ++n) acc[m][n] = (f32x4)0.0f;

#pragma unroll
        for (int m = 0; m < 2; ++m)
#pragma unroll
            for (int n = 0; n < 8; ++n) {
                acc[m][n] = __builtin_amdgcn_mfma_f32_16x16x32_bf16(qh[m], kh[n], acc[m][n], 0, 0, 0);
                acc[m][n] = __builtin_amdgcn_mfma_f32_16x16x32_bf16(qh[m], kl[n], acc[m][n], 0, 0, 0);
                acc[m][n] = __builtin_amdgcn_mfma_f32_16x16x32_bf16(ql[m], kh[n], acc[m][n], 0, 0, 0);
            }

        // masked softmax over k per row q, then scale and stage to LDS
#pragma unroll
        for (int m = 0; m < 2; ++m) {
#pragma unroll
            for (int r = 0; r < 4; ++r) {
                float mx = -1e30f;
#pragma unroll
                for (int n = 0; n < 8; ++n) mx = fmaxf(mx, acc[m][n][r] + cbias[n]);
#pragma unroll
                for (int off = 1; off < 16; off <<= 1) mx = fmaxf(mx, __shfl_xor(mx, off));
                float p[8], sum = 0.0f;
#pragma unroll
                for (int n = 0; n < 8; ++n) {
                    p[n] = __expf(acc[m][n][r] + cbias[n] - mx);
                    sum += p[n];
                }
#pragma unroll
                for (int off = 1; off < 16; off <<= 1) sum += __shfl_xor(sum, off);
                int   qlocal = m * 16 + dgrp * 4 + r;
                float scale  = rowsw[qt * 32 + qlocal] / sum;
#pragma unroll
                for (int n = 0; n < 8; ++n)
                    S8[qlocal][(n * 16 + colk) * 9 + h] = p[n] * scale * cswr[n];
            }
        }
        __syncthreads();

        // epilogue: h-contiguous 32B stores, * h2h2t[q][k]
        {
            int kx = (h & 1) * 64 + lane;
#pragma unroll
            for (int it = 0; it < 8; ++it) {
                int qlocal = (h >> 1) * 8 + it;
                int q = qt * 32 + qlocal;
                const float* srow = &S8[qlocal][kx * 9];
                float hh = (h2t[0][q] * h2t[0][kx] + h2t[1][q] * h2t[1][kx] +
                            h2t[2][q] * h2t[2][kx]) * 0.57735026918962576f;
                float4 o0 = {srow[0] * hh, srow[1] * hh, srow[2] * hh, srow[3] * hh};
                float4 o1 = {srow[4] * hh, srow[5] * hh, srow[6] * hh, srow[7] * hh};
                size_t ob = (((size_t)bl * 128 + q) * 128 + kx) * 8;
                *(float4*)(outp + ob)     = o0;
                *(float4*)(outp + ob + 4) = o1;
            }
        }
        __syncthreads();
    }
}

// ------------------------------- host --------------------------------------
extern "C" void kernel_launch(void* const* d_in, const int* in_sizes, int n_in,
                              void* d_out, int out_size, void* d_ws, size_t ws_size,
                              hipStream_t stream) {
    const float* g2  = (const float*)d_in[0];
    const float* h2  = (const float*)d_in[1];
    const int*   mk  = (const int*)d_in[2];       // int32 or byte-packed bool
    const float* sw  = (const float*)d_in[3];
    const float* W   = (const float*)d_in[4];
    float*       out = (float*)d_out;
    char*        ws  = (char*)d_ws;

    int*            flag  = (int*)ws;
    unsigned short* wt_hi = (unsigned short*)(ws + FLAG_BYTES);
    unsigned short* wt_lo = (unsigned short*)(ws + FLAG_BYTES + WT_BYTES / 2);
    float*          qk    = (float*)(ws + FLAG_BYTES + WT_BYTES);

    size_t head = (size_t)FLAG_BYTES + WT_BYTES;
    size_t avail = (ws_size > head) ? ws_size - head : 0;
    int slots = (int)(avail / QK_SLAB_BYTES);
    if (slots > NBL) slots = NBL;
    if (slots < 1)   slots = 1;

    // mask element count = 131072; scan n/4 words (valid for both dtypes)
    k_detect_mask<<<dim3(1), dim3(256), 0, stream>>>(
        (const unsigned int*)mk, in_sizes[2] / 4, flag);
    k0_prep_w<<<dim3(256), dim3(256), 0, stream>>>(W, wt_hi, wt_lo);

    for (int bl0 = 0; bl0 < NBL; bl0 += slots) {
        int cnt = NBL - bl0; if (cnt > slots) cnt = slots;
        k1_gemm_qk<<<dim3(cnt), dim3(512), 0, stream>>>(g2, wt_hi, wt_lo, qk, bl0);
        k2_attn_out<<<dim3(cnt), dim3(512), 0, stream>>>(qk, h2, mk, sw, flag, out, bl0);
    }
}